// Round 2
// baseline (335.769 us; speedup 1.0000x reference)
//
#include <hip/hip_runtime.h>

#define B_SZ 8192
#define D_SZ 4096
#define ROWCHUNKS 512
#define ROWS_PER 16   // B_SZ / ROWCHUNKS

// ws layout (float index):
//  [0,D)      mean  sum (all)
//  [D,2D)     mean  sum (class 1)
//  [2D,3D)    lsd   sum (all)
//  [3D,4D)    lsd   sum (class 1)
//  [4D,5D)    z     sum (all)
//  [5D,6D)    z     sum (class 1)
//  [6D,7D)    z^2   sum (all)
//  [7D,8D)    z^2   sum (class 1)
//  [8D]=cnt1  [8D+1]=logdet sum all  [8D+2]=logdet sum class1
//  doubles at float index 8D+8: S0,S1,Lsum0,Lsum1
constexpr int OFF_SCALAR = 8 * D_SZ;
constexpr int OFF_DBL    = 8 * D_SZ + 8;
constexpr size_t WS_CLEAR_BYTES = (size_t)(8 * D_SZ + 8) * 4 + 4 * 8;

__global__ __launch_bounds__(256)
void count_logdet_kernel(const int* __restrict__ target,
                         const float* __restrict__ logdet,
                         float* __restrict__ ws) {
    float c = 0.f, a = 0.f, o = 0.f;
    for (int i = blockIdx.x * 256 + threadIdx.x; i < B_SZ; i += gridDim.x * 256) {
        const float m  = (target[i] == 1) ? 1.f : 0.f;
        const float ld = logdet[i];
        c += m; a += ld; o += ld * m;
    }
    for (int off = 32; off > 0; off >>= 1) {
        c += __shfl_down(c, off);
        a += __shfl_down(a, off);
        o += __shfl_down(o, off);
    }
    if ((threadIdx.x & 63) == 0) {
        atomicAdd(ws + OFF_SCALAR + 0, c);   // exact: integer-valued, < 2^24
        atomicAdd(ws + OFF_SCALAR + 1, a);
        atomicAdd(ws + OFF_SCALAR + 2, o);
    }
}

// Masked column sums of {mean, log_sd, z, z^2}, "all" + "class1" variants.
// grid = (D/1024, ROWCHUNKS) = (4, 512) = 2048 blocks -> 8 blocks/CU, 32 waves/CU.
// Each thread owns 4 consecutive columns (float4 loads), ROWS_PER rows.
__global__ __launch_bounds__(256, 8)
void colsum_kernel(const float* __restrict__ z,
                   const float* __restrict__ mean,
                   const float* __restrict__ lsd,
                   const int* __restrict__ target,
                   float* __restrict__ ws) {
    const int col = blockIdx.x * 1024 + threadIdx.x * 4;
    const int r0  = blockIdx.y * ROWS_PER;

    float4 amA = {0,0,0,0}, am1 = {0,0,0,0};   // mean: all, class1
    float4 alA = {0,0,0,0}, al1 = {0,0,0,0};   // log_sd
    float4 azA = {0,0,0,0}, az1 = {0,0,0,0};   // z
    float4 aqA = {0,0,0,0}, aq1 = {0,0,0,0};   // z^2

#pragma unroll 4
    for (int i = r0; i < r0 + ROWS_PER; ++i) {
        const size_t base = (size_t)i * D_SZ + col;
        const float4 vm = *(const float4*)(mean + base);
        const float4 vl = *(const float4*)(lsd + base);
        const float4 vz = *(const float4*)(z + base);
        const float  mk = (target[i] == 1) ? 1.f : 0.f;   // wave-uniform -> s_load

        amA.x += vm.x; amA.y += vm.y; amA.z += vm.z; amA.w += vm.w;
        am1.x = fmaf(vm.x, mk, am1.x); am1.y = fmaf(vm.y, mk, am1.y);
        am1.z = fmaf(vm.z, mk, am1.z); am1.w = fmaf(vm.w, mk, am1.w);

        alA.x += vl.x; alA.y += vl.y; alA.z += vl.z; alA.w += vl.w;
        al1.x = fmaf(vl.x, mk, al1.x); al1.y = fmaf(vl.y, mk, al1.y);
        al1.z = fmaf(vl.z, mk, al1.z); al1.w = fmaf(vl.w, mk, al1.w);

        azA.x += vz.x; azA.y += vz.y; azA.z += vz.z; azA.w += vz.w;
        az1.x = fmaf(vz.x, mk, az1.x); az1.y = fmaf(vz.y, mk, az1.y);
        az1.z = fmaf(vz.z, mk, az1.z); az1.w = fmaf(vz.w, mk, az1.w);

        const float q0 = vz.x * vz.x, q1 = vz.y * vz.y;
        const float q2 = vz.z * vz.z, q3 = vz.w * vz.w;
        aqA.x += q0; aqA.y += q1; aqA.z += q2; aqA.w += q3;
        aq1.x = fmaf(q0, mk, aq1.x); aq1.y = fmaf(q1, mk, aq1.y);
        aq1.z = fmaf(q2, mk, aq1.z); aq1.w = fmaf(q3, mk, aq1.w);
    }

#define EMIT4(seg, v) \
    atomicAdd(ws + (seg) * D_SZ + col + 0, (v).x); \
    atomicAdd(ws + (seg) * D_SZ + col + 1, (v).y); \
    atomicAdd(ws + (seg) * D_SZ + col + 2, (v).z); \
    atomicAdd(ws + (seg) * D_SZ + col + 3, (v).w);

    EMIT4(0, amA) EMIT4(1, am1)
    EMIT4(2, alA) EMIT4(3, al1)
    EMIT4(4, azA) EMIT4(5, az1)
    EMIT4(6, aqA) EMIT4(7, aq1)
#undef EMIT4
}

// One thread per column d: write mu/lsd outputs, accumulate scalar sums.
__global__ __launch_bounds__(256)
void finalize_cols_kernel(float* __restrict__ ws, float* __restrict__ out) {
    const int d = blockIdx.x * 256 + threadIdx.x;
    const float cnt1 = ws[OFF_SCALAR];
    const float cnt0 = (float)B_SZ - cnt1;

    const float ma = ws[0 * D_SZ + d], m1 = ws[1 * D_SZ + d];
    const float la = ws[2 * D_SZ + d], l1 = ws[3 * D_SZ + d];
    const float za = ws[4 * D_SZ + d], z1 = ws[5 * D_SZ + d];
    const float qa = ws[6 * D_SZ + d], q1 = ws[7 * D_SZ + d];

    const float mu1 = m1 / cnt1, mu0 = (ma - m1) / cnt0;
    const float ls1 = l1 / cnt1, ls0 = (la - l1) / cnt0;

    // outputs: [0]=prior, [1,1+2D)=mus (class-major), [1+2D,1+4D)=lsds, [1+4D..]=lp
    out[1 + d]             = mu0;
    out[1 + D_SZ + d]      = mu1;
    out[1 + 2 * D_SZ + d]  = ls0;
    out[1 + 3 * D_SZ + d]  = ls1;

    const float z0 = za - z1, q0 = qa - q1;
    const double w0 = 0.5 * exp(-2.0 * (double)ls0);
    const double w1 = 0.5 * exp(-2.0 * (double)ls1);
    // sum_{i in c} (z - mu)^2 = Q_c - 2 mu_c Z_c + cnt_c mu_c^2
    double S0 = w0 * ((double)q0 - 2.0 * (double)mu0 * (double)z0 + (double)cnt0 * (double)mu0 * (double)mu0);
    double S1 = w1 * ((double)q1 - 2.0 * (double)mu1 * (double)z1 + (double)cnt1 * (double)mu1 * (double)mu1);
    double L0 = (double)ls0;
    double L1 = (double)ls1;

    for (int off = 32; off > 0; off >>= 1) {
        S0 += __shfl_down(S0, off);
        S1 += __shfl_down(S1, off);
        L0 += __shfl_down(L0, off);
        L1 += __shfl_down(L1, off);
    }
    if ((threadIdx.x & 63) == 0) {
        double* wd = (double*)(ws + OFF_DBL);
        atomicAdd(wd + 0, S0);
        atomicAdd(wd + 1, S1);
        atomicAdd(wd + 2, L0);
        atomicAdd(wd + 3, L1);
    }
}

__global__ void finalize_scalars_kernel(const float* __restrict__ ws, float* __restrict__ out) {
    const double LOG2PI = 1.8378770664093453;
    const double* wd = (const double*)(ws + OFF_DBL);
    const double S0 = wd[0], S1 = wd[1], L0 = wd[2], L1 = wd[3];
    const double cnt1 = (double)ws[OFF_SCALAR];
    const double cnt0 = (double)B_SZ - cnt1;
    const double ld_all = (double)ws[OFF_SCALAR + 1];
    const double ld1s   = (double)ws[OFF_SCALAR + 2];

    const double ldm1 = ld1s / cnt1;
    const double ldm0 = (ld_all - ld1s) / cnt0;

    const double c0 = -0.5 * LOG2PI * (double)D_SZ - L0;
    const double c1 = -0.5 * LOG2PI * (double)D_SZ - L1;
    const double lp0 = c0 - S0 / cnt0;
    const double lp1 = c1 - S1 / cnt1;

    out[1 + 4 * D_SZ + 0] = (float)lp0;
    out[1 + 4 * D_SZ + 1] = (float)lp1;
    out[0] = (float)(0.5 * ((lp0 + ldm0) + (lp1 + ldm1)));
}

extern "C" void kernel_launch(void* const* d_in, const int* in_sizes, int n_in,
                              void* d_out, int out_size, void* d_ws, size_t ws_size,
                              hipStream_t stream) {
    const float* z      = (const float*)d_in[0];
    const float* mean   = (const float*)d_in[1];
    const float* log_sd = (const float*)d_in[2];
    const int*   target = (const int*)d_in[3];
    const float* logdet = (const float*)d_in[4];
    float* out = (float*)d_out;
    float* ws  = (float*)d_ws;

    hipMemsetAsync(d_ws, 0, WS_CLEAR_BYTES, stream);

    count_logdet_kernel<<<16, 256, 0, stream>>>(target, logdet, ws);

    dim3 grid(D_SZ / 1024, ROWCHUNKS);   // 4 x 512 = 2048 blocks
    colsum_kernel<<<grid, 256, 0, stream>>>(z, mean, log_sd, target, ws);

    finalize_cols_kernel<<<D_SZ / 256, 256, 0, stream>>>(ws, out);
    finalize_scalars_kernel<<<1, 1, 0, stream>>>(ws, out);
}

// Round 3
// 109.191 us; speedup vs baseline: 3.0751x; 3.0751x over previous
//
#include <hip/hip_runtime.h>

#define B_SZ 8192
#define D_SZ 4096

// ws layout (float index), R = number of row-chunks (runtime, pow2 <= 128):
//  partials  [0, R*8*D)          : partial[(r*8+seg)*D + col]
//            seg: 0=mean_all 1=mean_c1 2=lsd_all 3=lsd_c1 4=z_all 5=z_c1 6=z2_all 7=z2_c1
//  reduced   [R*8*D, R*8*D+8*D)  : reduced[seg*D + col]
//  scalars   [sc, sc+8)          : 0=cnt1 1=logdet_all 2=logdet_c1   (sc = R*8*D + 8*D)
//  doubles   at float idx sc+8   : S0,S1,L0,L1  (8B-aligned: sc is even)

__global__ __launch_bounds__(256)
void count_logdet_kernel(const int* __restrict__ target,
                         const float* __restrict__ logdet,
                         float* __restrict__ ws, int sc_off) {
    float c = 0.f, a = 0.f, o = 0.f;
    for (int i = blockIdx.x * 256 + threadIdx.x; i < B_SZ; i += gridDim.x * 256) {
        const float m  = (target[i] == 1) ? 1.f : 0.f;
        const float ld = logdet[i];
        c += m; a += ld; o += ld * m;
    }
    for (int off = 32; off > 0; off >>= 1) {
        c += __shfl_down(c, off);
        a += __shfl_down(a, off);
        o += __shfl_down(o, off);
    }
    if ((threadIdx.x & 63) == 0) {
        atomicAdd(ws + sc_off + 0, c);   // exact: integer-valued, < 2^24
        atomicAdd(ws + sc_off + 1, a);
        atomicAdd(ws + sc_off + 2, o);
    }
}

// Stage 1: masked column partial-sums, NO atomics. grid = (4, R, 3).
// blockIdx.z selects array: 0=mean, 1=log_sd, 2=z (z also accumulates z^2).
// Each thread owns 4 consecutive cols (float4), ROWS_PER rows, stores partials.
template <int ROWS_PER>
__global__ __launch_bounds__(256, 8)
void colsum_kernel(const float* __restrict__ z,
                   const float* __restrict__ mean,
                   const float* __restrict__ lsd,
                   const int* __restrict__ target,
                   float* __restrict__ ws) {
    const int col = blockIdx.x * 1024 + threadIdx.x * 4;
    const int i0  = blockIdx.y * ROWS_PER;
    float* pbase  = ws + (size_t)blockIdx.y * 8 * D_SZ;

    if (blockIdx.z == 2) {
        float4 aA = {0,0,0,0}, a1 = {0,0,0,0};
        float4 qA = {0,0,0,0}, q1 = {0,0,0,0};
#pragma unroll 8
        for (int i = i0; i < i0 + ROWS_PER; ++i) {
            const float4 v = *(const float4*)(z + (size_t)i * D_SZ + col);
            const float mk = (target[i] == 1) ? 1.f : 0.f;
            aA.x += v.x; aA.y += v.y; aA.z += v.z; aA.w += v.w;
            a1.x = fmaf(v.x, mk, a1.x); a1.y = fmaf(v.y, mk, a1.y);
            a1.z = fmaf(v.z, mk, a1.z); a1.w = fmaf(v.w, mk, a1.w);
            const float qx = v.x*v.x, qy = v.y*v.y, qz = v.z*v.z, qw = v.w*v.w;
            qA.x += qx; qA.y += qy; qA.z += qz; qA.w += qw;
            q1.x = fmaf(qx, mk, q1.x); q1.y = fmaf(qy, mk, q1.y);
            q1.z = fmaf(qz, mk, q1.z); q1.w = fmaf(qw, mk, q1.w);
        }
        *(float4*)(pbase + 4 * D_SZ + col) = aA;
        *(float4*)(pbase + 5 * D_SZ + col) = a1;
        *(float4*)(pbase + 6 * D_SZ + col) = qA;
        *(float4*)(pbase + 7 * D_SZ + col) = q1;
    } else {
        const float* p = (blockIdx.z == 0) ? mean : lsd;
        const int segbase = blockIdx.z * 2;
        float4 aA = {0,0,0,0}, a1 = {0,0,0,0};
#pragma unroll 8
        for (int i = i0; i < i0 + ROWS_PER; ++i) {
            const float4 v = *(const float4*)(p + (size_t)i * D_SZ + col);
            const float mk = (target[i] == 1) ? 1.f : 0.f;
            aA.x += v.x; aA.y += v.y; aA.z += v.z; aA.w += v.w;
            a1.x = fmaf(v.x, mk, a1.x); a1.y = fmaf(v.y, mk, a1.y);
            a1.z = fmaf(v.z, mk, a1.z); a1.w = fmaf(v.w, mk, a1.w);
        }
        *(float4*)(pbase + (segbase + 0) * D_SZ + col) = aA;
        *(float4*)(pbase + (segbase + 1) * D_SZ + col) = a1;
    }
}

// Stage 2: reduce partials over r. One thread per (seg,col) pair, s in [0, 8*D).
__global__ __launch_bounds__(256)
void reduce_partials_kernel(const float* __restrict__ ws,
                            float* __restrict__ red, int R) {
    const int s = blockIdx.x * 256 + threadIdx.x;
    float acc = 0.f;
#pragma unroll 8
    for (int r = 0; r < R; ++r) acc += ws[(size_t)r * 8 * D_SZ + s];
    red[s] = acc;
}

// One thread per column d: write mu/lsd outputs, accumulate scalar sums.
__global__ __launch_bounds__(256)
void finalize_cols_kernel(const float* __restrict__ red,
                          float* __restrict__ ws, int sc_off,
                          float* __restrict__ out) {
    const int d = blockIdx.x * 256 + threadIdx.x;
    const float cnt1 = ws[sc_off];
    const float cnt0 = (float)B_SZ - cnt1;

    const float ma = red[0 * D_SZ + d], m1 = red[1 * D_SZ + d];
    const float la = red[2 * D_SZ + d], l1 = red[3 * D_SZ + d];
    const float za = red[4 * D_SZ + d], z1 = red[5 * D_SZ + d];
    const float qa = red[6 * D_SZ + d], q1 = red[7 * D_SZ + d];

    const float mu1 = m1 / cnt1, mu0 = (ma - m1) / cnt0;
    const float ls1 = l1 / cnt1, ls0 = (la - l1) / cnt0;

    // outputs: [0]=prior, [1,1+2D)=mus (class-major), [1+2D,1+4D)=lsds, [1+4D..]=lp
    out[1 + d]             = mu0;
    out[1 + D_SZ + d]      = mu1;
    out[1 + 2 * D_SZ + d]  = ls0;
    out[1 + 3 * D_SZ + d]  = ls1;

    const float z0 = za - z1, q0 = qa - q1;
    const double w0 = 0.5 * exp(-2.0 * (double)ls0);
    const double w1 = 0.5 * exp(-2.0 * (double)ls1);
    // sum_{i in c} (z - mu)^2 = Q_c - 2 mu_c Z_c + cnt_c mu_c^2
    double S0 = w0 * ((double)q0 - 2.0 * (double)mu0 * (double)z0 + (double)cnt0 * (double)mu0 * (double)mu0);
    double S1 = w1 * ((double)q1 - 2.0 * (double)mu1 * (double)z1 + (double)cnt1 * (double)mu1 * (double)mu1);
    double L0 = (double)ls0;
    double L1 = (double)ls1;

    for (int off = 32; off > 0; off >>= 1) {
        S0 += __shfl_down(S0, off);
        S1 += __shfl_down(S1, off);
        L0 += __shfl_down(L0, off);
        L1 += __shfl_down(L1, off);
    }
    if ((threadIdx.x & 63) == 0) {
        double* wd = (double*)(ws + sc_off + 8);
        atomicAdd(wd + 0, S0);
        atomicAdd(wd + 1, S1);
        atomicAdd(wd + 2, L0);
        atomicAdd(wd + 3, L1);
    }
}

__global__ void finalize_scalars_kernel(const float* __restrict__ ws, int sc_off,
                                        float* __restrict__ out) {
    const double LOG2PI = 1.8378770664093453;
    const double* wd = (const double*)(ws + sc_off + 8);
    const double S0 = wd[0], S1 = wd[1], L0 = wd[2], L1 = wd[3];
    const double cnt1 = (double)ws[sc_off];
    const double cnt0 = (double)B_SZ - cnt1;
    const double ld_all = (double)ws[sc_off + 1];
    const double ld1s   = (double)ws[sc_off + 2];

    const double ldm1 = ld1s / cnt1;
    const double ldm0 = (ld_all - ld1s) / cnt0;

    const double c0 = -0.5 * LOG2PI * (double)D_SZ - L0;
    const double c1 = -0.5 * LOG2PI * (double)D_SZ - L1;
    const double lp0 = c0 - S0 / cnt0;
    const double lp1 = c1 - S1 / cnt1;

    out[1 + 4 * D_SZ + 0] = (float)lp0;
    out[1 + 4 * D_SZ + 1] = (float)lp1;
    out[0] = (float)(0.5 * ((lp0 + ldm0) + (lp1 + ldm1)));
}

extern "C" void kernel_launch(void* const* d_in, const int* in_sizes, int n_in,
                              void* d_out, int out_size, void* d_ws, size_t ws_size,
                              hipStream_t stream) {
    const float* z      = (const float*)d_in[0];
    const float* mean   = (const float*)d_in[1];
    const float* log_sd = (const float*)d_in[2];
    const int*   target = (const int*)d_in[3];
    const float* logdet = (const float*)d_in[4];
    float* out = (float*)d_out;
    float* ws  = (float*)d_ws;

    // Pick largest R (row-chunks) whose partial buffer fits in ws.
    int R = 128;
    while (R > 8) {
        const size_t need = ((size_t)R * 8 * D_SZ + 8 * D_SZ + 8) * 4 + 32;
        if (need <= ws_size) break;
        R >>= 1;
    }
    const int red_off = R * 8 * D_SZ;
    const int sc_off  = red_off + 8 * D_SZ;

    // Only the scalar/double tail needs zeroing (partials/reduced fully overwritten).
    hipMemsetAsync((char*)d_ws + (size_t)sc_off * 4, 0, 8 * 4 + 4 * 8, stream);

    count_logdet_kernel<<<16, 256, 0, stream>>>(target, logdet, ws, sc_off);

    const dim3 grid(D_SZ / 1024, R, 3);
    switch (R) {
        case 128: colsum_kernel<B_SZ/128><<<grid, 256, 0, stream>>>(z, mean, log_sd, target, ws); break;
        case  64: colsum_kernel<B_SZ/64 ><<<grid, 256, 0, stream>>>(z, mean, log_sd, target, ws); break;
        case  32: colsum_kernel<B_SZ/32 ><<<grid, 256, 0, stream>>>(z, mean, log_sd, target, ws); break;
        case  16: colsum_kernel<B_SZ/16 ><<<grid, 256, 0, stream>>>(z, mean, log_sd, target, ws); break;
        default:  colsum_kernel<B_SZ/8  ><<<grid, 256, 0, stream>>>(z, mean, log_sd, target, ws); break;
    }

    reduce_partials_kernel<<<8 * D_SZ / 256, 256, 0, stream>>>(ws, ws + red_off, R);
    finalize_cols_kernel<<<D_SZ / 256, 256, 0, stream>>>(ws + red_off, ws, sc_off, out);
    finalize_scalars_kernel<<<1, 1, 0, stream>>>(ws, sc_off, out);
}